// Round 3
// baseline (232.488 us; speedup 1.0000x reference)
//
#include <hip/hip_runtime.h>

#define NB 16
#define NC 8
#define HW (512 * 512)
#define BLOCKS_PER_B 64
#define NTHREADS 256

// ws layout (floats): [0, NB*64)           : S[b][ci][ck]
//                     [NB*64, NB*64+NB*8)  : n[b][ck]
//                     [NB*72]              : ce_sum
#define WS_FLOATS (NB * NC * NC + NB * NC + 1)

__device__ __forceinline__ float wave_reduce(float v) {
#pragma unroll
  for (int off = 32; off > 0; off >>= 1) v += __shfl_xor(v, off, 64);
  return v;
}

// grid = (64, 16), 256 threads, __launch_bounds__(256,4):
//   4 blocks/CU * 256 CU = 1024 = exact grid size -> zero residency tail.
//   float2 loads keep live VGPRs ~115 so the 128-VGPR cap doesn't spill.
//   Each thread does exactly 8 iterations (131072 float2-groups / 16384 thr).
__global__ __launch_bounds__(NTHREADS, 4)
void jce_main(const float* __restrict__ pred, const int* __restrict__ target,
              float* __restrict__ ws) {
  const int b = blockIdx.y;
  const int tid = threadIdx.x;
  const float* predb = pred + (size_t)b * NC * HW;
  const int2* tgt2 = (const int2*)(target + (size_t)b * HW);

  // per-thread accumulators — all statically indexed so they stay in VGPRs
  float S[NC][NC];
  float cnt[NC];
  float ce = 0.0f;
#pragma unroll
  for (int i = 0; i < NC; ++i) {
    cnt[i] = 0.0f;
#pragma unroll
    for (int k = 0; k < NC; ++k) S[i][k] = 0.0f;
  }

  const int ng = HW / 2;  // float2 groups per batch = 131072
  for (int g = blockIdx.x * NTHREADS + tid; g < ng; g += BLOCKS_PER_B * NTHREADS) {
    const int2 t2 = tgt2[g];
    float2 p2[NC];
#pragma unroll
    for (int c = 0; c < NC; ++c)
      p2[c] = ((const float2*)(predb + (size_t)c * HW))[g];

#pragma unroll
    for (int j = 0; j < 2; ++j) {
      const int tc = (j == 0) ? t2.x : t2.y;
      float pv[NC];
#pragma unroll
      for (int c = 0; c < NC; ++c) pv[c] = (j == 0) ? p2[c].x : p2[c].y;

      // cross entropy: logsumexp - pred[tc]. Inputs ~N(0,1): no max needed.
      float es = 0.0f;
#pragma unroll
      for (int c = 0; c < NC; ++c) es += __expf(pv[c]);
      const float lse = __logf(es);

      // masked accumulation into S / cnt, plus pred[tc] pickup
      float ptc = 0.0f;
#pragma unroll
      for (int k = 0; k < NC; ++k) {
        const float msk = (tc == k) ? 1.0f : 0.0f;
        cnt[k] += msk;
        ptc = fmaf(msk, pv[k], ptc);
#pragma unroll
        for (int ci = 0; ci < NC; ++ci)
          S[ci][k] = fmaf(msk, pv[ci], S[ci][k]);
      }
      ce += lse - ptc;
    }
  }

  // wave-level butterfly reduction of all 73 partials (static indices)
#pragma unroll
  for (int i = 0; i < NC; ++i) {
#pragma unroll
    for (int k = 0; k < NC; ++k) S[i][k] = wave_reduce(S[i][k]);
    cnt[i] = wave_reduce(cnt[i]);
  }
  ce = wave_reduce(ce);

  // cross-wave reduction through LDS, then one atomicAdd per value per block
  __shared__ float red[NTHREADS / 64][NC * NC + NC + 1];
  const int wave = tid >> 6, lane = tid & 63;
  if (lane == 0) {
#pragma unroll
    for (int i = 0; i < NC; ++i) {
#pragma unroll
      for (int k = 0; k < NC; ++k) red[wave][i * NC + k] = S[i][k];
      red[wave][NC * NC + i] = cnt[i];
    }
    red[wave][NC * NC + NC] = ce;
  }
  __syncthreads();
  if (tid < NC * NC + NC + 1) {
    float v = 0.0f;
#pragma unroll
    for (int w = 0; w < NTHREADS / 64; ++w) v += red[w][tid];
    if (tid < NC * NC)
      atomicAdd(&ws[b * (NC * NC) + tid], v);
    else if (tid < NC * NC + NC)
      atomicAdd(&ws[NB * NC * NC + b * NC + (tid - NC * NC)], v);
    else
      atomicAdd(&ws[NB * NC * NC + NB * NC], v);
  }
}

__global__ __launch_bounds__(NTHREADS)
void jce_finalize(const float* __restrict__ ws, float* __restrict__ out) {
  const int tid = threadIdx.x;
  float acc = 0.0f;
  for (int idx = tid; idx < NB * NC * NC; idx += NTHREADS) {
    const int b = idx >> 6, ci = (idx >> 3) & 7, ck = idx & 7;
    if (ci == ck) continue;
    const float n_ck = ws[NB * NC * NC + b * NC + ck];
    const float n_ci = ws[NB * NC * NC + b * NC + ci];
    const float M = ws[b * (NC * NC) + ci * NC + ck] / n_ck;
    const float dg = ws[b * (NC * NC) + ci * NC + ci] / n_ci;
    acc += logf(0.5f + 0.5f * (dg - M));
  }
  acc = wave_reduce(acc);
  __shared__ float red[NTHREADS / 64];
  const int wave = tid >> 6, lane = tid & 63;
  if (lane == 0) red[wave] = acc;
  __syncthreads();
  if (tid == 0) {
    float tot = 0.0f;
#pragma unroll
    for (int w = 0; w < NTHREADS / 64; ++w) tot += red[w];
    const float jl = -tot / (float)NB;
    const float ce = ws[NB * NC * NC + NB * NC] / ((float)NB * (float)HW);
    out[0] = jl + ce;
  }
}

extern "C" void kernel_launch(void* const* d_in, const int* in_sizes, int n_in,
                              void* d_out, int out_size, void* d_ws, size_t ws_size,
                              hipStream_t stream) {
  const float* pred = (const float*)d_in[0];
  const int* target = (const int*)d_in[1];
  float* out = (float*)d_out;
  float* ws = (float*)d_ws;

  hipMemsetAsync(ws, 0, WS_FLOATS * sizeof(float), stream);
  dim3 grid(BLOCKS_PER_B, NB);
  jce_main<<<grid, NTHREADS, 0, stream>>>(pred, target, ws);
  jce_finalize<<<1, NTHREADS, 0, stream>>>(ws, out);
}

// Round 4
// 212.407 us; speedup vs baseline: 1.0945x; 1.0945x over previous
//
#include <hip/hip_runtime.h>

#define NB 16
#define NC 8
#define HW (512 * 512)
#define BLOCKS_PER_B 32
#define NTHREADS 256

// ws layout (floats): [0, NB*64)           : S[b][ci][ck]
//                     [NB*64, NB*64+NB*8)  : n[b][ck]
//                     [NB*72]              : ce_sum
#define WS_FLOATS (NB * NC * NC + NB * NC + 1)

__device__ __forceinline__ float wave_reduce(float v) {
#pragma unroll
  for (int off = 32; off > 0; off >>= 1) v += __shfl_xor(v, off, 64);
  return v;
}

// grid = (32, 16) = 512 blocks = exactly 2 blocks/CU; 8192 threads/batch.
// Each thread: exactly 8 float4 iterations (65536 groups / 8192 threads).
// __launch_bounds__(256, 2): VGPR cap 256 -> the 64-float S accumulator
// array stays in registers. Round-3 evidence: cap 128 made the compiler
// spill S wholesale (VGPR_Count=64, WRITE_SIZE=34MB scratch traffic,
// 86.8us at 17% HBM). Registers > residency here.
__global__ __launch_bounds__(NTHREADS, 2)
void jce_main(const float* __restrict__ pred, const int* __restrict__ target,
              float* __restrict__ ws) {
  const int b = blockIdx.y;
  const int tid = threadIdx.x;
  const float* predb = pred + (size_t)b * NC * HW;
  const int4* tgt4 = (const int4*)(target + (size_t)b * HW);

  // per-thread accumulators — all statically indexed so they stay in VGPRs
  float S[NC][NC];
  float cnt[NC];
  float ce = 0.0f;
#pragma unroll
  for (int i = 0; i < NC; ++i) {
    cnt[i] = 0.0f;
#pragma unroll
    for (int k = 0; k < NC; ++k) S[i][k] = 0.0f;
  }

  const int ng = HW / 4;  // float4 groups per batch = 65536
#pragma unroll 2
  for (int g = blockIdx.x * NTHREADS + tid; g < ng; g += BLOCKS_PER_B * NTHREADS) {
    const int4 t4 = tgt4[g];
    float4 p4[NC];
#pragma unroll
    for (int c = 0; c < NC; ++c)
      p4[c] = ((const float4*)(predb + (size_t)c * HW))[g];

#pragma unroll
    for (int j = 0; j < 4; ++j) {
      const int tc = (j == 0) ? t4.x : (j == 1) ? t4.y : (j == 2) ? t4.z : t4.w;
      float pv[NC];
#pragma unroll
      for (int c = 0; c < NC; ++c)
        pv[c] = (j == 0) ? p4[c].x : (j == 1) ? p4[c].y : (j == 2) ? p4[c].z : p4[c].w;

      // cross entropy: logsumexp - pred[tc]. Inputs ~N(0,1): no max needed.
      float es = 0.0f;
#pragma unroll
      for (int c = 0; c < NC; ++c) es += __expf(pv[c]);
      const float lse = __logf(es);

      // masked accumulation into S / cnt, plus pred[tc] pickup
      float ptc = 0.0f;
#pragma unroll
      for (int k = 0; k < NC; ++k) {
        const float msk = (tc == k) ? 1.0f : 0.0f;
        cnt[k] += msk;
        ptc = fmaf(msk, pv[k], ptc);
#pragma unroll
        for (int ci = 0; ci < NC; ++ci)
          S[ci][k] = fmaf(msk, pv[ci], S[ci][k]);
      }
      ce += lse - ptc;
    }
  }

  // wave-level butterfly reduction of all 73 partials (static indices)
#pragma unroll
  for (int i = 0; i < NC; ++i) {
#pragma unroll
    for (int k = 0; k < NC; ++k) S[i][k] = wave_reduce(S[i][k]);
    cnt[i] = wave_reduce(cnt[i]);
  }
  ce = wave_reduce(ce);

  // cross-wave reduction through LDS, then one atomicAdd per value per block
  __shared__ float red[NTHREADS / 64][NC * NC + NC + 1];
  const int wave = tid >> 6, lane = tid & 63;
  if (lane == 0) {
#pragma unroll
    for (int i = 0; i < NC; ++i) {
#pragma unroll
      for (int k = 0; k < NC; ++k) red[wave][i * NC + k] = S[i][k];
      red[wave][NC * NC + i] = cnt[i];
    }
    red[wave][NC * NC + NC] = ce;
  }
  __syncthreads();
  if (tid < NC * NC + NC + 1) {
    float v = 0.0f;
#pragma unroll
    for (int w = 0; w < NTHREADS / 64; ++w) v += red[w][tid];
    if (tid < NC * NC)
      atomicAdd(&ws[b * (NC * NC) + tid], v);
    else if (tid < NC * NC + NC)
      atomicAdd(&ws[NB * NC * NC + b * NC + (tid - NC * NC)], v);
    else
      atomicAdd(&ws[NB * NC * NC + NB * NC], v);
  }
}

__global__ __launch_bounds__(NTHREADS)
void jce_finalize(const float* __restrict__ ws, float* __restrict__ out) {
  const int tid = threadIdx.x;
  float acc = 0.0f;
  for (int idx = tid; idx < NB * NC * NC; idx += NTHREADS) {
    const int b = idx >> 6, ci = (idx >> 3) & 7, ck = idx & 7;
    if (ci == ck) continue;
    const float n_ck = ws[NB * NC * NC + b * NC + ck];
    const float n_ci = ws[NB * NC * NC + b * NC + ci];
    const float M = ws[b * (NC * NC) + ci * NC + ck] / n_ck;
    const float dg = ws[b * (NC * NC) + ci * NC + ci] / n_ci;
    acc += logf(0.5f + 0.5f * (dg - M));
  }
  acc = wave_reduce(acc);
  __shared__ float red[NTHREADS / 64];
  const int wave = tid >> 6, lane = tid & 63;
  if (lane == 0) red[wave] = acc;
  __syncthreads();
  if (tid == 0) {
    float tot = 0.0f;
#pragma unroll
    for (int w = 0; w < NTHREADS / 64; ++w) tot += red[w];
    const float jl = -tot / (float)NB;
    const float ce = ws[NB * NC * NC + NB * NC] / ((float)NB * (float)HW);
    out[0] = jl + ce;
  }
}

extern "C" void kernel_launch(void* const* d_in, const int* in_sizes, int n_in,
                              void* d_out, int out_size, void* d_ws, size_t ws_size,
                              hipStream_t stream) {
  const float* pred = (const float*)d_in[0];
  const int* target = (const int*)d_in[1];
  float* out = (float*)d_out;
  float* ws = (float*)d_ws;

  hipMemsetAsync(ws, 0, WS_FLOATS * sizeof(float), stream);
  dim3 grid(BLOCKS_PER_B, NB);
  jce_main<<<grid, NTHREADS, 0, stream>>>(pred, target, ws);
  jce_finalize<<<1, NTHREADS, 0, stream>>>(ws, out);
}